// Round 2
// baseline (254.696 us; speedup 1.0000x reference)
//
#include <hip/hip_runtime.h>

#define N_NODES 100000
#define N_EDGES 1600000
#define IN_C    128
#define OUT_C   64

#define SB_NODES 512                               // nodes per super-bucket
#define NSB  ((N_NODES + SB_NODES - 1) / SB_NODES) // 196
#define SCAP 9216                                  // mean 8163, +11 sigma
#define ACHUNK 4096                                // edges per sorta block
#define NABLK ((N_EDGES + ACHUNK - 1) / ACHUNK)    // 391

// ---- bf16x2 helpers ----
__device__ inline unsigned pack_bf16x2(float lo, float hi) {
    unsigned a = __float_as_uint(lo), b2 = __float_as_uint(hi);
    a  += 0x7fff + ((a  >> 16) & 1);               // RNE
    b2 += 0x7fff + ((b2 >> 16) & 1);
    return (a >> 16) | (b2 & 0xffff0000u);
}
__device__ inline float bf_lo(unsigned v) { return __uint_as_float(v << 16); }
__device__ inline float bf_hi(unsigned v) { return __uint_as_float(v & 0xffff0000u); }

// ---------------- zero super-bucket cursors ----------------
__global__ void zero_kernel(int* __restrict__ cursor) {
    int i = blockIdx.x * blockDim.x + threadIdx.x;
    if (i < NSB) cursor[i] = 0;
}

// ------ pass A: partition edges into 196 coarse dst-buckets (512 nodes) -----
// entry = s*512 + (d & 511); per-wave private histograms kill LDS-atomic
// contention; chunked reservations keep store-line sharing minimal.
__global__ __launch_bounds__(256) void sorta_kernel(const int* __restrict__ ei,
                                                    int* __restrict__ cursor,
                                                    int* __restrict__ sb) {
    __shared__ int histW[4][NSB];
    __shared__ int base_[NSB];
    __shared__ int cur[NSB];
    const int t = threadIdx.x, w = t >> 6;
    const long long e0 = (long long)blockIdx.x * ACHUNK;
    for (int i = t; i < 4 * NSB; i += 256) (&histW[0][0])[i] = 0;
    __syncthreads();
    const int* dsts = ei + N_EDGES;
#pragma unroll
    for (int k = 0; k < ACHUNK / 1024; ++k) {
        long long i4 = e0 / 4 + t + k * 256;
        if (i4 * 4 + 3 < N_EDGES) {
            int4 d = *(const int4*)&dsts[i4 * 4];
            atomicAdd(&histW[w][d.x >> 9], 1);
            atomicAdd(&histW[w][d.y >> 9], 1);
            atomicAdd(&histW[w][d.z >> 9], 1);
            atomicAdd(&histW[w][d.w >> 9], 1);
        }
    }
    __syncthreads();
    if (t < NSB) {
        int c = histW[0][t] + histW[1][t] + histW[2][t] + histW[3][t];
        base_[t] = c ? atomicAdd(&cursor[t], c) : 0;
        cur[t] = 0;
    }
    __syncthreads();
#pragma unroll
    for (int k = 0; k < ACHUNK / 1024; ++k) {
        long long i4 = e0 / 4 + t + k * 256;
        if (i4 * 4 + 3 < N_EDGES) {
            int4 s4 = *(const int4*)&ei[i4 * 4];
            int4 d4 = *(const int4*)&dsts[i4 * 4];
            int sv[4] = {s4.x, s4.y, s4.z, s4.w};
            int dv[4] = {d4.x, d4.y, d4.z, d4.w};
#pragma unroll
            for (int j = 0; j < 4; ++j) {
                int bk = dv[j] >> 9;
                int pos = base_[bk] + atomicAdd(&cur[bk], 1);
                if (pos < SCAP)
                    sb[bk * SCAP + pos] = sv[j] * SB_NODES + (dv[j] & (SB_NODES - 1));
            }
        }
    }
}

// ------ pass B: per coarse bucket, LDS counting sort by node -> CSR ---------
__global__ __launch_bounds__(256) void sortb_kernel(const int* __restrict__ cursor,
                                                    int* __restrict__ sb,
                                                    float* __restrict__ dinv,
                                                    int* __restrict__ rowbeg,
                                                    int* __restrict__ rowend) {
    __shared__ int hist[SB_NODES];
    __shared__ int pref[SB_NODES + 1];
    __shared__ int cur[SB_NODES];
    __shared__ int sc[256];
    __shared__ int sorted[SCAP];                   // 36.9 KB
    const int t = threadIdx.x, b = blockIdx.x;
    for (int k = t; k < SB_NODES; k += 256) { hist[k] = 0; cur[k] = 0; }
    __syncthreads();
    int m = cursor[b]; if (m > SCAP) m = SCAP;
    int* bb = sb + b * SCAP;
    for (int i = t; i < m; i += 256) atomicAdd(&hist[bb[i] & (SB_NODES - 1)], 1);
    __syncthreads();
    int c0 = hist[2 * t], c1 = hist[2 * t + 1];
    int tsum = c0 + c1;
    sc[t] = tsum;
    __syncthreads();
    for (int off = 1; off < 256; off <<= 1) {      // Hillis-Steele inclusive
        int u = (t >= off) ? sc[t - off] : 0;
        __syncthreads();
        sc[t] += u;
        __syncthreads();
    }
    int excl = sc[t] - tsum;
    pref[2 * t]     = excl;
    pref[2 * t + 1] = excl + c0;
    if (t == 255) pref[SB_NODES] = sc[255];
    __syncthreads();
    for (int i = t; i < m; i += 256) {
        int e = bb[i];
        int dl = e & (SB_NODES - 1);
        int pos = pref[dl] + atomicAdd(&cur[dl], 1);
        sorted[pos] = e >> 9;                      // plain src id
    }
    __syncthreads();
    for (int i = t; i < m; i += 256) bb[i] = sorted[i];   // coalesced writeback
    for (int k = t; k < SB_NODES; k += 256) {
        int n = b * SB_NODES + k;
        if (n < N_NODES) {
            rowbeg[n] = b * SCAP + pref[k];
            rowend[n] = b * SCAP + pref[k + 1];
            dinv[n]   = rsqrtf((float)hist[k] + 1.0f);    // +1 self-loop
        }
    }
}

// ------- xws = bf16( dinv[n] * (x @ W) ) : 32 nodes/block, 128 B rows -------
#define XN  32
#define SXS 132
__global__ __launch_bounds__(256) void xws_kernel(const float* __restrict__ x,
                                                  const float* __restrict__ W,
                                                  const float* __restrict__ dinv,
                                                  unsigned* __restrict__ xwsh) {
    __shared__ float sW[IN_C * OUT_C];     // 32 KB
    __shared__ float sx[XN * SXS];         // 16.9 KB
    const int t = threadIdx.x;
    const int n0 = blockIdx.x * XN;
    const float4* W4 = (const float4*)W;
    float4* sW4 = (float4*)sW;
#pragma unroll
    for (int k = 0; k < 8; ++k) sW4[t + k * 256] = W4[t + k * 256];
#pragma unroll
    for (int k = 0; k < 4; ++k) {
        int idx = (t + k * 256) * 4;
        int r = idx >> 7, kk = idx & 127;
        int n = n0 + r;
        float4 v = (n < N_NODES) ? *(const float4*)&x[(long long)n * IN_C + kk]
                                 : make_float4(0.f, 0.f, 0.f, 0.f);
        *(float4*)&sx[r * SXS + kk] = v;
    }
    __syncthreads();
    const int r  = t >> 4;
    const int cq = (t & 15) << 2;
    float4 a0 = make_float4(0.f,0.f,0.f,0.f), a1 = a0;
#pragma unroll 8
    for (int k = 0; k < IN_C; ++k) {
        float x0 = sx[r * SXS + k];
        float x1 = sx[(r + 16) * SXS + k];
        float4 wv = *(const float4*)&sW[(k << 6) + cq];
        a0.x = fmaf(x0, wv.x, a0.x); a0.y = fmaf(x0, wv.y, a0.y);
        a0.z = fmaf(x0, wv.z, a0.z); a0.w = fmaf(x0, wv.w, a0.w);
        a1.x = fmaf(x1, wv.x, a1.x); a1.y = fmaf(x1, wv.y, a1.y);
        a1.z = fmaf(x1, wv.z, a1.z); a1.w = fmaf(x1, wv.w, a1.w);
    }
    int na = n0 + r, nb = n0 + r + 16;
    if (na < N_NODES) {
        float di = dinv[na];
        uint2 o = make_uint2(pack_bf16x2(a0.x * di, a0.y * di),
                             pack_bf16x2(a0.z * di, a0.w * di));
        *(uint2*)&xwsh[(long long)na * 32 + ((t & 15) << 1)] = o;
    }
    if (nb < N_NODES) {
        float di = dinv[nb];
        uint2 o = make_uint2(pack_bf16x2(a1.x * di, a1.y * di),
                             pack_bf16x2(a1.z * di, a1.w * di));
        *(uint2*)&xwsh[(long long)nb * 32 + ((t & 15) << 1)] = o;
    }
}

// ------- pull aggregation + fused epilogue: wave per node ------------------
// srcs indices are wave-uniform -> scalar loads (no shfl broadcast); lanes
// 0-31 gather edge 2u's 128B bf16 row, lanes 32-63 edge 2u+1's (one cndmask).
__global__ __launch_bounds__(256) void aggnode_kernel(
    const int* __restrict__ rowbeg, const int* __restrict__ rowend,
    const int* __restrict__ srcs, const float* __restrict__ dinv,
    const unsigned* __restrict__ xwsh, const float* __restrict__ b,
    const float* __restrict__ Wc, const float* __restrict__ bc,
    float2* __restrict__ p, float2* __restrict__ q) {
    const int lane = threadIdx.x & 63;
    int node = __builtin_amdgcn_readfirstlane(blockIdx.x * 4 + (threadIdx.x >> 6));
    const int beg = rowbeg[node], end = rowend[node];   // scalar loads
    const int half = lane >> 5, hl = lane & 31;
    float ax0 = 0.f, ay0 = 0.f, ax1 = 0.f, ay1 = 0.f;
    float ax2 = 0.f, ay2 = 0.f, ax3 = 0.f, ay3 = 0.f;
    int i = beg;
    for (; i + 7 < end; i += 8) {                  // 4 dual-row loads in flight
        int s0 = srcs[i + 0], s1 = srcs[i + 1], s2 = srcs[i + 2], s3 = srcs[i + 3];
        int s4 = srcs[i + 4], s5 = srcs[i + 5], s6 = srcs[i + 6], s7 = srcs[i + 7];
        unsigned v0 = xwsh[(half ? s1 : s0) * 32 + hl];
        unsigned v1 = xwsh[(half ? s3 : s2) * 32 + hl];
        unsigned v2 = xwsh[(half ? s5 : s4) * 32 + hl];
        unsigned v3 = xwsh[(half ? s7 : s6) * 32 + hl];
        ax0 += bf_lo(v0); ay0 += bf_hi(v0);
        ax1 += bf_lo(v1); ay1 += bf_hi(v1);
        ax2 += bf_lo(v2); ay2 += bf_hi(v2);
        ax3 += bf_lo(v3); ay3 += bf_hi(v3);
    }
    for (; i + 1 < end; i += 2) {                  // pair tail
        int sa = srcs[i], sb2 = srcs[i + 1];
        unsigned v = xwsh[(half ? sb2 : sa) * 32 + hl];
        ax0 += bf_lo(v); ay0 += bf_hi(v);
    }
    if (i < end) {                                 // single tail (half 0 only)
        int s = srcs[i];
        unsigned v = xwsh[s * 32 + hl];
        if (!half) { ax1 += bf_lo(v); ay1 += bf_hi(v); }
    }
    float ax = (ax0 + ax1) + (ax2 + ax3);
    float ay = (ay0 + ay1) + (ay2 + ay3);
    ax += __shfl(ax, hl + 32);                     // combine halves (lanes 0-31)
    ay += __shfl(ay, hl + 32);
    unsigned vs = xwsh[node * 32 + hl];            // self-loop (dinv folded)
    ax += bf_lo(vs); ay += bf_hi(vs);
    float di = dinv[node];
    float2 b2 = ((const float2*)b)[hl];
    float h0 = fmaxf(fmaf(di, ax, b2.x), 0.f);
    float h1 = fmaxf(fmaf(di, ay, b2.y), 0.f);
    float4 wcs = ((const float4*)Wc)[hl];
    float4 wcd = ((const float4*)(Wc + 2 * OUT_C))[hl];
    float p0 = h0 * wcs.x + h1 * wcs.z;
    float p1 = h0 * wcs.y + h1 * wcs.w;
    float q0 = h0 * wcd.x + h1 * wcd.z;
    float q1 = h0 * wcd.y + h1 * wcd.w;
#pragma unroll
    for (int off = 16; off; off >>= 1) {           // width-32 reduce (lanes 0-31)
        p0 += __shfl_down(p0, off); p1 += __shfl_down(p1, off);
        q0 += __shfl_down(q0, off); q1 += __shfl_down(q1, off);
    }
    if (lane == 0) {
        p[node] = make_float2(p0 + bc[0], p1 + bc[1]);
        q[node] = make_float2(q0, q1);
    }
}

// ------------ edge outputs: out[e] = p[src] + q[dst], 4 edges/thread --------
__global__ void edge_kernel(const int* __restrict__ ei, const int* __restrict__ nei,
                            const float2* __restrict__ p, const float2* __restrict__ q,
                            float4* __restrict__ out4) {
    int idx = blockIdx.x * blockDim.x + threadIdx.x;
    if (idx >= 2 * N_EDGES / 4) return;
    int e4 = idx * 4;
    const int *S, *D;
    int off;
    if (e4 < N_EDGES) { S = ei;  D = ei  + N_EDGES; off = e4; }
    else              { S = nei; D = nei + N_EDGES; off = e4 - N_EDGES; }
    int4 s4 = *(const int4*)&S[off];
    int4 d4 = *(const int4*)&D[off];
    float2 pa = p[s4.x], qa = q[d4.x];
    float2 pb = p[s4.y], qb = q[d4.y];
    float2 pc = p[s4.z], qc = q[d4.z];
    float2 pd = p[s4.w], qd = q[d4.w];
    out4[idx * 2]     = make_float4(pa.x + qa.x, pa.y + qa.y, pb.x + qb.x, pb.y + qb.y);
    out4[idx * 2 + 1] = make_float4(pc.x + qc.x, pc.y + qc.y, pd.x + qd.x, pd.y + qd.y);
}

extern "C" void kernel_launch(void* const* d_in, const int* in_sizes, int n_in,
                              void* d_out, int out_size, void* d_ws, size_t ws_size,
                              hipStream_t stream) {
    const float* x   = (const float*)d_in[0];   // [N,128]
    const int*   ei  = (const int*)  d_in[1];   // [2,E]
    const int*   nei = (const int*)  d_in[2];   // [2,E]
    const float* W   = (const float*)d_in[3];   // [128,64]
    const float* b   = (const float*)d_in[4];   // [64]
    const float* Wc  = (const float*)d_in[5];   // [128,2]
    const float* bc  = (const float*)d_in[6];   // [2]

    // workspace (ints): end = 3902720 + 196*9216 = 5709056 ints = 22.8 MB
    int*      wsI    = (int*)d_ws;
    float*    dinv   = (float*)wsI;              // N           [0, 100352)
    unsigned* xwsh   = (unsigned*)(wsI + 100352);// N*32 bf16x2 [100352, 3300352)
    float*    p      = (float*)(wsI + 3300352);  // N*2         [3300352, 3501056)
    float*    q      = (float*)(wsI + 3501056);  // N*2         [3501056, 3701760)
    int*      cursor = wsI + 3701760;            // NSB         [3701760, 3702016)
    int*      rowbeg = wsI + 3702016;            // N           [3702016, 3802368)
    int*      rowend = wsI + 3802368;            // N           [3802368, 3902720)
    int*      sbuf   = wsI + 3902720;            // NSB*SCAP

    const int B = 256;
    zero_kernel<<<1, B, 0, stream>>>(cursor);
    sorta_kernel<<<NABLK, B, 0, stream>>>(ei, cursor, sbuf);
    sortb_kernel<<<NSB, B, 0, stream>>>(cursor, sbuf, dinv, rowbeg, rowend);
    xws_kernel<<<(N_NODES + XN - 1) / XN, B, 0, stream>>>(x, W, dinv, xwsh);
    aggnode_kernel<<<N_NODES / 4, B, 0, stream>>>(rowbeg, rowend, sbuf, dinv, xwsh,
                                                  b, Wc, bc, (float2*)p, (float2*)q);
    edge_kernel<<<(2 * N_EDGES / 4 + B - 1) / B, B, 0, stream>>>(
        ei, nei, (const float2*)p, (const float2*)q, (float4*)d_out);
}